// Round 9
// baseline (5171.818 us; speedup 1.0000x reference)
//
#include <hip/hip_runtime.h>
#include <hip/hip_bf16.h>
#include <stdint.h>

typedef unsigned short u16;
typedef uint32_t u32;
typedef unsigned long long u64;
typedef float f32x4 __attribute__((ext_vector_type(4)));
typedef __bf16 bf16x8 __attribute__((ext_vector_type(8)));

__device__ inline u16 f2bf(float f) {
  __bf16 h = (__bf16)f;                 // RTNE
  return __builtin_bit_cast(u16, h);
}
__device__ inline f32x4 mfma16(bf16x8 a, bf16x8 b, f32x4 c) {
  return __builtin_amdgcn_mfma_f32_16x16x32_bf16(a, b, c, 0, 0, 0);
}
// split 8 contiguous fp32 into bf16 hi + lo fragments (cached loads)
__device__ inline void cvt8(const float* p, bf16x8& h, bf16x8& l) {
  f32x4 u = *(const f32x4*)p;
  f32x4 v = *(const f32x4*)(p + 4);
#pragma unroll
  for (int i = 0; i < 4; ++i) {
    float a = u[i]; __bf16 ah = (__bf16)a; h[i] = ah; l[i] = (__bf16)(a - (float)ah);
    float b = v[i]; __bf16 bh = (__bf16)b; h[i + 4] = bh; l[i + 4] = (__bf16)(b - (float)bh);
  }
}
// gather 8 k-strided fp32 (stride 1024 floats) into bf16 hi + lo fragments
__device__ inline void gather8(const float* p, bf16x8& h, bf16x8& l) {
#pragma unroll
  for (int e = 0; e < 8; ++e) {
    float f = p[(size_t)e * 1024];
    __bf16 x = (__bf16)f;
    h[e] = x; l[e] = (__bf16)(f - (float)x);
  }
}

// ---- coherence-point (bypass) accessors ----
__device__ inline u64 ld64(const u64* p) {
  return __hip_atomic_load(p, __ATOMIC_RELAXED, __HIP_MEMORY_SCOPE_AGENT);
}
__device__ inline u32 ld32(const u32* p) {
  return __hip_atomic_load(p, __ATOMIC_RELAXED, __HIP_MEMORY_SCOPE_AGENT);
}
__device__ inline void st32(u32* p, u32 v) {
  __hip_atomic_store(p, v, __ATOMIC_RELAXED, __HIP_MEMORY_SCOPE_AGENT);
}

// bf16 state plane [32 b][1024 j], 64KB, k-contiguous layout (u16 units):
//   idx16(b,j) = (j>>3)<<8 | ((j>>2)&1)<<7 | (b&31)<<2 | (j&3)
// A wave fragment (8 k-elems, one row) = 2 coalesced ld64.
struct B16Pair { u64 a, b; };
__device__ inline bf16x8 ldfrag(const u64* base, int j8, int row) {
  B16Pair p;
  p.a = ld64(base + (j8 << 6) + row);
  p.b = ld64(base + (j8 << 6) + 32 + row);
  return __builtin_bit_cast(bf16x8, p);
}

struct RecArgs {
  const float* x;
  const float *W_ix, *W_ih, *W_ic, *W_fx, *W_fh, *W_fc, *W_cx, *W_ch;
  const float *W_ox, *W_oh, *W_oc;
  const float *b_i, *b_f, *b_c, *b_o;
  u32 *hB, *cB;          // bf16 state planes, 64KB each
  u32* flags;            // 5 arrays x 256 per-block epoch flags
  float* out;
};

// phase flag arrays
#define PA1 0
#define PA2 1
#define PB1 2
#define PB2 3
#define PIN 4

// Batch-split skewed barriers: arrive = flag store; wait = wave0 polls all
// 256 flags of that array (usually already set thanks to the phase skew).
__device__ inline void arriveF(u32* flags, int ph, u32 epv, int wg) {
  __syncthreads();                      // drain state stores to IF$ first
  if (threadIdx.x == 0) st32(flags + (ph << 8) + wg, epv);
}
__device__ inline void waitF(u32* flags, int ph, u32 epv) {
  if (threadIdx.x < 64) {
    const u32* f = flags + (ph << 8) + threadIdx.x * 4;
    int it = 0;
    for (;;) {
      u32 v0 = ld32(f), v1 = ld32(f + 1), v2 = ld32(f + 2), v3 = ld32(f + 3);
      if (__ballot((v0 >= epv) & (v1 >= epv) & (v2 >= epv) & (v3 >= epv)) == ~0ull)
        break;
      if (++it > 400000) break;
      __builtin_amdgcn_s_sleep(1);
    }
  }
  __syncthreads();
}

// ---- phase bodies as macros (guaranteed inline, static reg indexing) ----
#define PHASE1(HALF, TCUR, CF, CREG, BFV, OPRE, SW)                            \
  {                                                                            \
    f32x4 acc = {}, pc = {};                                                   \
    _Pragma("unroll")                                                          \
    for (int ks = 0; ks < 4; ++ks) {                                           \
      const int ka = kw + ks * 32 + kq;                                        \
      const int j8 = wave * 16 + ks * 4 + kgroup;                              \
      bf16x8 ah = ldfrag(H64, j8, mrow + (HALF) * 16);                         \
      bf16x8 xh, xl;                                                           \
      const float* xp =                                                        \
          a.x + ((size_t)((TCUR) * 32 + (HALF) * 16 + mrow) << 10) + ka;       \
      cvt8(xp, xh, xl);                                                        \
      acc = mfma16(xh, bxh[ks], acc);                                          \
      acc = mfma16(xl, bxh[ks], acc);                                          \
      acc = mfma16(xh, bxl[ks], acc);                                          \
      acc = mfma16(ah, bhh[ks], acc);                                          \
      acc = mfma16(ah, bhl[ks], acc);                                          \
      pc = mfma16(CF[ks], bch[ks], pc);                                        \
      pc = mfma16(CF[ks], bcl[ks], pc);                                        \
    }                                                                          \
    const bool take_pc = (col & 3) != 3;                                       \
    _Pragma("unroll")                                                          \
    for (int v = 0; v < 4; ++v)                                                \
      scr[(wave * 16 + rq + v) * 17 + col] = acc[v] + (take_pc ? pc[v] : 0.f); \
    __syncthreads();                                                           \
    if (tid < 64) {                                                            \
      float pre[4];                                                            \
      _Pragma("unroll")                                                        \
      for (int g = 0; g < 4; ++g) {                                            \
        float s = 0.f;                                                         \
        _Pragma("unroll")                                                      \
        for (int w = 0; w < 8; ++w)                                            \
          s += scr[(w * 16 + eb16) * 17 + ejj * 4 + g];                        \
        pre[g] = s;                                                            \
      }                                                                        \
      float iv = 1.f / (1.f + expf(-(pre[0] + bi)));                           \
      float fv = 1.f / (1.f + expf(-(pre[1] + (BFV))));                        \
      float cv = tanhf(pre[2] + bcv);                                          \
      CREG = fv * CREG + iv * cv;                                              \
      u32 cb = (u32)f2bf(CREG);                                                \
      u32 cpart = __shfl_xor(cb, 1);                                           \
      if ((tid & 1) == 0) st32(a.cB + (SW), cb | (cpart << 16));               \
      OPRE = pre[3] + bo;                                                      \
    }                                                                          \
  }

#define PHASE2(HALF, TCUR, CF, CREG, OPRE, SW)                                 \
  {                                                                            \
    f32x4 a2 = {};                                                             \
    _Pragma("unroll")                                                          \
    for (int ks = 0; ks < 4; ++ks) {                                           \
      const int j8 = wave * 16 + ks * 4 + kgroup;                              \
      CF[ks] = ldfrag(C64, j8, mrow + (HALF) * 16);                            \
      a2 = mfma16(CF[ks], bch[ks], a2);                                        \
      a2 = mfma16(CF[ks], bcl[ks], a2);                                        \
    }                                                                          \
    _Pragma("unroll")                                                          \
    for (int v = 0; v < 4; ++v)                                                \
      scr[(wave * 16 + rq + v) * 17 + col] = a2[v];                            \
    __syncthreads();                                                           \
    if (tid < 64) {                                                            \
      float s = OPRE;                                                          \
      _Pragma("unroll")                                                        \
      for (int w = 0; w < 8; ++w)                                              \
        s += scr[(w * 16 + eb16) * 17 + ejj * 4 + 3];                          \
      float ov = 1.f / (1.f + expf(-s));                                       \
      float hv = ov * tanhf(CREG);                                             \
      u32 hb = (u32)f2bf(hv);                                                  \
      u32 hpart = __shfl_xor(hb, 1);                                           \
      if ((tid & 1) == 0) st32(a.hB + (SW), hb | (hpart << 16));               \
      if ((TCUR) == 511) a.out[((HALF) * 16 + eb16) * 1024 + ej] = hv;         \
    }                                                                          \
  }

// Persistent LSTM, batch-split phase-skewed: 256 blocks x 512 threads.
// Halves A (rows 0-15) / B (rows 16-31) are independent chains; their
// barriers interleave so each barrier's latency hides under the other
// half's compute phase.
__global__ __launch_bounds__(512, 2) void lstm_rec(RecArgs a) {
  __shared__ float scr[8 * 16 * 17];       // [wave][row][col], padded stride

  const int tid = threadIdx.x;
  const int wg = blockIdx.x;
  const int j0 = wg * 4;
  const int lane = tid & 63;
  const int wave = tid >> 6;
  const int mrow = lane & 15;               // A-row lane index within half
  const int kgroup = lane >> 4;             // k sub-block 0..3
  const int kq = kgroup * 8;
  const int kw = wave * 128;                // per-wave K slice
  const int col = lane & 15;                // B/D column lane index
  const int rq = (lane >> 4) * 4;           // D row quad base

  const u64* H64 = (const u64*)a.hB;
  const u64* C64 = (const u64*)a.cB;

  // ---- one-time: B-fragments (weights) -> registers, hi/lo split ----
  const int fjj = col >> 2, fg = col & 3;   // col = jj*4 + g
  const int fj = j0 + fjj;
  const float* Wx = (fg == 0) ? a.W_ix : (fg == 1) ? a.W_fx : (fg == 2) ? a.W_cx : a.W_ox;
  const float* Wh = (fg == 0) ? a.W_ih : (fg == 1) ? a.W_fh : (fg == 2) ? a.W_ch : a.W_oh;
  const float* Wc = (fg == 0) ? a.W_ic : (fg == 1) ? a.W_fc : (fg == 3) ? a.W_oc : a.W_ic;

  bf16x8 bxh[4], bxl[4], bhh[4], bhl[4], bch[4], bcl[4];
#pragma unroll
  for (int ks = 0; ks < 4; ++ks) {
    const size_t k8 = (size_t)(kw + ks * 32 + kq);
    gather8(Wx + k8 * 1024 + fj, bxh[ks], bxl[ks]);
    gather8(Wh + k8 * 1024 + fj, bhh[ks], bhl[ks]);
    if (fg != 2) {
      gather8(Wc + k8 * 1024 + fj, bch[ks], bcl[ks]);
    } else {
      bf16x8 z = {};
      bch[ks] = z; bcl[ks] = z;
    }
  }

  // elementwise constants (threads 0..63 handle one half: 16 rows x 4 cols)
  const int eb16 = tid >> 2, ejj = tid & 3, ej = j0 + (tid & 3);
  const u32 swbase = ((u32)(ej >> 3) << 7) | ((u32)((ej >> 2) & 1) << 6)
                   | ((u32)(ej >> 1) & 1);
  const u32 sw0 = swbase | ((u32)eb16 << 1);          // half A row
  const u32 sw1 = swbase | ((u32)(eb16 + 16) << 1);   // half B row
  // ---- zero state: threads 0..127 cover all 32 rows (pairs) ----
  if (tid < 128 && (tid & 1) == 0) {
    const int zb = tid >> 2, zj = j0 + (tid & 3);
    const u32 zw = ((u32)(zj >> 3) << 7) | ((u32)((zj >> 2) & 1) << 6)
                 | ((u32)zb << 1) | ((u32)(zj >> 1) & 1);
    st32(a.hB + zw, 0u);
    st32(a.cB + zw, 0u);
  }
  float bi = 0.f, bfvA = 0.f, bfvB = 0.f, bcv = 0.f, bo = 0.f;
  if (tid < 64) {
    bi = a.b_i[ej];
    bfvA = a.b_f[eb16 * 1024 + ej];
    bfvB = a.b_f[(eb16 + 16) * 1024 + ej];
    bcv = a.b_c[ej];
    bo = a.b_o[ej];
  }
  arriveF(a.flags, PIN, 1, wg);
  waitF(a.flags, PIN, 1);

  float c_regA = 0.f, c_regB = 0.f, o_preA = 0.f, o_preB = 0.f;
  bf16x8 cfA[4] = {}, cfB[4] = {};          // carried c_{t-1} fragments

  // prologue: half A phase 1 of t=0 (state all zero, carried frags zero)
  PHASE1(0, 0, cfA, c_regA, bfvA, o_preA, sw0)
  arriveF(a.flags, PA1, 1, wg);

  for (int t = 0; t < 512; ++t) {
    if (t) waitF(a.flags, PB2, (u32)t);     // hB(t-1) ready
    PHASE1(1, t, cfB, c_regB, bfvB, o_preB, sw1)
    arriveF(a.flags, PB1, (u32)(t + 1), wg);

    waitF(a.flags, PA1, (u32)(t + 1));      // cA(t) ready
    PHASE2(0, t, cfA, c_regA, o_preA, sw0)
    arriveF(a.flags, PA2, (u32)(t + 1), wg);

    waitF(a.flags, PB1, (u32)(t + 1));      // cB(t) ready
    PHASE2(1, t, cfB, c_regB, o_preB, sw1)
    arriveF(a.flags, PB2, (u32)(t + 1), wg);

    if (t < 511) {
      waitF(a.flags, PA2, (u32)(t + 1));    // hA(t) ready
      PHASE1(0, t + 1, cfA, c_regA, bfvA, o_preA, sw0)
      arriveF(a.flags, PA1, (u32)(t + 2), wg);
    }
  }
}

extern "C" void kernel_launch(void* const* d_in, const int* in_sizes, int n_in,
                              void* d_out, int out_size, void* d_ws, size_t ws_size,
                              hipStream_t stream) {
  (void)in_sizes; (void)n_in; (void)out_size;
  RecArgs ra;
  ra.x    = (const float*)d_in[0];
  ra.W_ix = (const float*)d_in[1];
  ra.W_ih = (const float*)d_in[2];
  ra.W_ic = (const float*)d_in[3];
  ra.W_fx = (const float*)d_in[4];
  ra.W_fh = (const float*)d_in[5];
  ra.W_fc = (const float*)d_in[6];
  ra.W_cx = (const float*)d_in[7];
  ra.W_ch = (const float*)d_in[8];
  ra.W_ox = (const float*)d_in[9];
  ra.W_oh = (const float*)d_in[10];
  ra.W_oc = (const float*)d_in[11];
  ra.b_i  = (const float*)d_in[12];
  ra.b_f  = (const float*)d_in[13];
  ra.b_c  = (const float*)d_in[14];
  ra.b_o  = (const float*)d_in[15];

  char* ws = (char*)d_ws;
  size_t off = 0;
  auto alloc = [&](size_t bytes) {
    char* p = ws + off;
    off = (off + bytes + 255) & ~(size_t)255;
    return p;
  };
  ra.hB    = (u32*)alloc(32 * 1024 * 2);   // bf16 h plane, k-contiguous layout
  ra.cB    = (u32*)alloc(32 * 1024 * 2);   // bf16 c plane
  ra.flags = (u32*)alloc(5 * 256 * 4);     // 5 epoch-flag arrays
  ra.out   = (float*)d_out;
  if (off > ws_size) return;               // visible failure if ws too small

  (void)hipMemsetAsync(ra.flags, 0, 5 * 256 * 4, stream);

  void* args[] = {&ra};
  hipError_t e = hipLaunchCooperativeKernel((void*)lstm_rec, dim3(256), dim3(512),
                                            args, 0, stream);
  if (e != hipSuccess) {
    // co-residency still holds: 1 block/CU x 256 blocks on 256 CUs
    lstm_rec<<<dim3(256), dim3(512), 0, stream>>>(ra);
  }
}